// Round 8
// baseline (1143.906 us; speedup 1.0000x reference)
//
#include <hip/hip_runtime.h>
#include <hip/hip_bf16.h>

#define NN 50000
#define D 128
#define RR 4
#define NNZ 800000
#define NCHUNK 196            // ceil(NN/256)

typedef float v2f    __attribute__((ext_vector_type(2)));
typedef float f32x4  __attribute__((ext_vector_type(4)));
typedef short bf16x8 __attribute__((ext_vector_type(8)));

static __device__ __forceinline__ unsigned short f2b(float f)
{
    __hip_bfloat16 h = __float2bfloat16(f);      // RNE
    return *reinterpret_cast<unsigned short*>(&h);
}
static __device__ __forceinline__ float b2f(unsigned short u)
{
    union { unsigned u32; float f; } v; v.u32 = ((unsigned)u) << 16; return v.f;
}

// 32-lane sum reduction: 4 DPP steps (VALU pipe) + 1 ds_swizzle xor16.
// quad_perm[1,0,3,2]=0xB1 (xor1), quad_perm[2,3,0,1]=0x4E (xor2),
// row_half_mirror=0x141 (pairs 4-groups), row_mirror=0x140 (pairs 8-groups).
static __device__ __forceinline__ float redux32(float v)
{
    int i;
    i = __builtin_amdgcn_update_dpp(0, __float_as_int(v), 0xB1, 0xF, 0xF, true);
    v += __int_as_float(i);
    i = __builtin_amdgcn_update_dpp(0, __float_as_int(v), 0x4E, 0xF, 0xF, true);
    v += __int_as_float(i);
    i = __builtin_amdgcn_update_dpp(0, __float_as_int(v), 0x141, 0xF, 0xF, true);
    v += __int_as_float(i);
    i = __builtin_amdgcn_update_dpp(0, __float_as_int(v), 0x140, 0xF, 0xF, true);
    v += __int_as_float(i);
    v += __int_as_float(__builtin_amdgcn_ds_swizzle(__float_as_int(v), 0x401F));
    return v;
}

// ============================ CSR build =====================================
__global__ __launch_bounds__(256) void hist_kernel(
    const int* __restrict__ rows, int* __restrict__ cnt)
{
    const int r = blockIdx.y;
    const int e = blockIdx.x * 256 + threadIdx.x;      // NNZ = 3125*256 exact
    atomicAdd(&cnt[r * NN + rows[(size_t)r * NNZ + e]], 1);
}

__global__ __launch_bounds__(256) void scanA_kernel(
    const int* __restrict__ cnt, int* __restrict__ bsum)
{
    const int r = blockIdx.y, bx = blockIdx.x, t = threadIdx.x;
    const int idx = bx * 256 + t;
    int v = (idx < NN) ? cnt[r * NN + idx] : 0;
#pragma unroll
    for (int off = 32; off; off >>= 1) v += __shfl_xor(v, off);
    __shared__ int ws4[4];
    if ((t & 63) == 0) ws4[t >> 6] = v;
    __syncthreads();
    if (t == 0) bsum[r * NCHUNK + bx] = ws4[0] + ws4[1] + ws4[2] + ws4[3];
}

__global__ __launch_bounds__(256) void scanB_kernel(int* __restrict__ bsum)
{
    __shared__ int s[256];
    const int t = threadIdx.x;
    for (int r = 0; r < RR; ++r) {
        int v = (t < NCHUNK) ? bsum[r * NCHUNK + t] : 0;
        s[t] = v;
        __syncthreads();
        for (int off = 1; off < 256; off <<= 1) {
            int u = (t >= off) ? s[t - off] : 0;
            __syncthreads();
            s[t] += u;
            __syncthreads();
        }
        if (t < NCHUNK) bsum[r * NCHUNK + t] = s[t] - v;   // exclusive
        __syncthreads();
    }
}

__global__ __launch_bounds__(256) void scanC_kernel(
    const int* __restrict__ cnt, const int* __restrict__ bsum,
    int* __restrict__ rowptr, int* __restrict__ cursor)
{
    const int r = blockIdx.y, bx = blockIdx.x, t = threadIdx.x;
    const int idx = bx * 256 + t;
    int v = (idx < NN) ? cnt[r * NN + idx] : 0;
    __shared__ int s[256];
    s[t] = v;
    __syncthreads();
    for (int off = 1; off < 256; off <<= 1) {
        int u = (t >= off) ? s[t - off] : 0;
        __syncthreads();
        s[t] += u;
        __syncthreads();
    }
    const int excl = bsum[r * NCHUNK + bx] + s[t] - v;
    if (idx <= NN) rowptr[r * (NN + 1) + idx] = excl;
    if (idx < NN)  cursor[r * NN + idx] = excl;
}

__global__ __launch_bounds__(256) void fill_kernel(
    const int* __restrict__ rows, const int* __restrict__ cols,
    int* __restrict__ cursor, int* __restrict__ perm)
{
    const int r = blockIdx.y;
    const int e = blockIdx.x * 256 + threadIdx.x;
    const int row = rows[(size_t)r * NNZ + e];
    const int pos = atomicAdd(&cursor[r * NN + row], 1);
    perm[(size_t)r * NNZ + pos] = cols[(size_t)r * NNZ + e];
}

// ============================ x -> bf16 hi/lo ===============================
__global__ __launch_bounds__(256) void convx_kernel(
    const float* __restrict__ x,
    unsigned short* __restrict__ xh, unsigned short* __restrict__ xl)
{
    const int i = blockIdx.x * 256 + threadIdx.x;      // over 1,600,000 float4s
    f32x4 v = ((const f32x4*)x)[i];
    ushort4 hv, lv;
#pragma unroll
    for (int j = 0; j < 4; ++j) {
        unsigned short hb = f2b(v[j]);
        ((unsigned short*)&hv)[j] = hb;
        ((unsigned short*)&lv)[j] = f2b(v[j] - b2f(hb));
    }
    ((ushort4*)xh)[i] = hv;
    ((ushort4*)xl)[i] = lv;
}

// ================== composed weights PT = (W_s^T * WX)^T ====================
// PT[m][col][k] = sum_j WX[j][col] * W_s[j][k];  m=0..4 -> WC slabs, 5..9 -> WD.
// fp32 accumulate, then split bf16 hi/lo. 10*128*128 outputs.
__global__ __launch_bounds__(256) void convpt_kernel(
    const float* __restrict__ Wself, const float* __restrict__ Wring,
    const float* __restrict__ WC, const float* __restrict__ WD,
    unsigned short* __restrict__ PTh, unsigned short* __restrict__ PTl)
{
    const int idx = blockIdx.x * 256 + threadIdx.x;    // 163840
    const int m   = idx >> 14;
    const int rem = idx & 16383;
    const int col = rem >> 7;
    const int kk  = rem & 127;
    const float* WX = (m < 5) ? WC : WD;
    const int s = (m < 5) ? m : m - 5;
    const float* WS = (s == 0) ? Wself : Wring + (size_t)(s - 1) * 16384;
    float acc = 0.f;
#pragma unroll 4
    for (int j = 0; j < 128; ++j)
        acc += WX[j * 128 + col] * WS[j * 128 + kk];
    unsigned short hb = f2b(acc);
    PTh[idx] = hb;
    PTl[idx] = f2b(acc - b2f(hb));
}

// ============================ CSR gather (split out) ========================
// y[ring][row][:] = sum over edges (row,col): odn[col] * x[col][:], stored as
// bf16 hi/lo pair (exact to 2^-16 rel). One wave per (row, ring).
__global__ __launch_bounds__(256) void gather2_kernel(
    const float* __restrict__ x, const float* __restrict__ odn,
    const int* __restrict__ rp, const int* __restrict__ pm,
    unsigned short* __restrict__ yh, unsigned short* __restrict__ yl)
{
    const int cr = blockIdx.y;
    const int t = threadIdx.x;
    const int row = blockIdx.x * 4 + (t >> 6);      // 12500*4 = 50000 exact
    const int l  = t & 63;
    const int h  = l >> 5;                          // edge parity (0/1)
    const int dq = l & 31;                          // float4 index in row
    const int* rpr = rp + (size_t)cr * (NN + 1);
    const int s = rpr[row], e = rpr[row + 1];
    const int* pmr = pm + (size_t)cr * NNZ;

    f32x4 acc = {0.f, 0.f, 0.f, 0.f};
    int i = s;
    for (; i + 8 <= e; i += 8) {
        int c0 = pmr[i + h],     c1 = pmr[i + 2 + h];
        int c2 = pmr[i + 4 + h], c3 = pmr[i + 6 + h];
        float o0 = odn[c0], o1 = odn[c1], o2 = odn[c2], o3 = odn[c3];
        f32x4 v0 = *(const f32x4*)&x[(size_t)c0 * D + dq * 4];
        f32x4 v1 = *(const f32x4*)&x[(size_t)c1 * D + dq * 4];
        f32x4 v2 = *(const f32x4*)&x[(size_t)c2 * D + dq * 4];
        f32x4 v3 = *(const f32x4*)&x[(size_t)c3 * D + dq * 4];
        acc += v0 * o0 + v1 * o1 + v2 * o2 + v3 * o3;
    }
    for (; i + h < e; i += 2) {
        int c = pmr[i + h];
        acc += (*(const f32x4*)&x[(size_t)c * D + dq * 4]) * odn[c];
    }
#pragma unroll
    for (int j = 0; j < 4; ++j) acc[j] += __shfl_xor(acc[j], 32);

    if (h == 0) {
        ushort4 hv, lv;
#pragma unroll
        for (int j = 0; j < 4; ++j) {
            unsigned short hb = f2b(acc[j]);
            ((unsigned short*)&hv)[j] = hb;
            ((unsigned short*)&lv)[j] = f2b(acc[j] - b2f(hb));
        }
        const size_t base = ((size_t)cr * NN + row) * D + dq * 4;
        *(ushort4*)&yh[base] = hv;
        *(ushort4*)&yl[base] = lv;
    }
}

// ============================ shared helpers ================================
__device__ __forceinline__ int sidx(int r, int s)
{
    if (r > s) { int t = r; r = s; s = t; }
    return r * 5 + s - (r * (r + 1)) / 2;
}

// SB[m][node][col] f32, XOR-swizzled to kill the node-stride bank conflict.
__device__ __forceinline__ int sboff(int m, int node, int col)
{
    return (((m * 16 + node) * 128 + col) * 4) ^ ((node & 7) << 4);
}

// ======================= FUSED Zc/Zd GEMM + interaction =====================
// Block = 512 thr (8 waves) = 16 nodes.  Zc/Zd[n][m] = A_s[n] @ PT_m
// (A_0 = x, A_s = y[s-1]; all pre-split bf16 hi/lo in global; no in-kernel
// splitting, no z intermediate).  Swapped MFMA operands: A = PT[col][k]
// (M=out-col), B = node-data (N=node) -> C-frag = [node][4 consec cols] ->
// b128 SB writes.  Phase C: 32 lanes per node, f32x4 cols/lane, DPP reduce.
__global__ __launch_bounds__(512, 4) void fused2_kernel(
    const unsigned short* __restrict__ xh, const unsigned short* __restrict__ xl,
    const unsigned short* __restrict__ yh, const unsigned short* __restrict__ yl,
    const unsigned short* __restrict__ PTh, const unsigned short* __restrict__ PTl,
    const float* __restrict__ att_w, const float* __restrict__ att_b,
    const float* __restrict__ idn, float* __restrict__ out)
{
    __shared__ __align__(16) char LB[81920];    // SB: 10 x 16 x 128 f32

    const int t  = threadIdx.x;
    const int w  = t >> 6;
    const int l  = t & 63;
    const int lr = l & 15;
    const int lk = l >> 4;
    const int n0 = blockIdx.x * 16;

    // ---------------- GEMM: wave w owns col-tile w (16 cols) of all 10 m ----
    f32x4 acc[10];
#pragma unroll
    for (int m = 0; m < 10; ++m) acc[m] = (f32x4){0.f, 0.f, 0.f, 0.f};

#pragma unroll
    for (int s = 0; s < 5; ++s) {
        const unsigned short* bhq = (s == 0 ? xh : yh + (size_t)(s - 1) * NN * D)
                                    + (size_t)(n0 + lr) * D + lk * 8;
        const unsigned short* blq = (s == 0 ? xl : yl + (size_t)(s - 1) * NN * D)
                                    + (size_t)(n0 + lr) * D + lk * 8;
        const int arow = (w * 16 + lr) * 128 + lk * 8;
        const unsigned short* a0h = PTh + (size_t)s * 16384 + arow;
        const unsigned short* a0l = PTl + (size_t)s * 16384 + arow;
        const unsigned short* a1h = PTh + (size_t)(5 + s) * 16384 + arow;
        const unsigned short* a1l = PTl + (size_t)(5 + s) * 16384 + arow;
#pragma unroll
        for (int ks = 0; ks < 4; ++ks) {
            bf16x8 bh  = *(const bf16x8*)(bhq + ks * 32);
            bf16x8 bl  = *(const bf16x8*)(blq + ks * 32);
            bf16x8 ah0 = *(const bf16x8*)(a0h + ks * 32);
            bf16x8 al0 = *(const bf16x8*)(a0l + ks * 32);
            bf16x8 ah1 = *(const bf16x8*)(a1h + ks * 32);
            bf16x8 al1 = *(const bf16x8*)(a1l + ks * 32);
            // (Ah,Bh) + (Al,Bh) + (Ah,Bl); drop Al*Bl (~2^-16)
            acc[s] = __builtin_amdgcn_mfma_f32_16x16x32_bf16(ah0, bh, acc[s], 0, 0, 0);
            acc[s] = __builtin_amdgcn_mfma_f32_16x16x32_bf16(al0, bh, acc[s], 0, 0, 0);
            acc[s] = __builtin_amdgcn_mfma_f32_16x16x32_bf16(ah0, bl, acc[s], 0, 0, 0);
            acc[5 + s] = __builtin_amdgcn_mfma_f32_16x16x32_bf16(ah1, bh, acc[5 + s], 0, 0, 0);
            acc[5 + s] = __builtin_amdgcn_mfma_f32_16x16x32_bf16(al1, bh, acc[5 + s], 0, 0, 0);
            acc[5 + s] = __builtin_amdgcn_mfma_f32_16x16x32_bf16(ah1, bl, acc[5 + s], 0, 0, 0);
        }
    }

    // C-frag: node = lr, 4 consecutive out-cols (w*16 + lk*4 + q) -> one b128
#pragma unroll
    for (int m = 0; m < 10; ++m)
        *(f32x4*)(LB + sboff(m, lr, w * 16 + lk * 4)) = acc[m];
    __syncthreads();

    // ---------------- phase C: 32 lanes per node ---------------------------
    const int lg = l & 31;               // lane in group: cols 4lg..4lg+3
    const int nd = w * 2 + (l >> 5);     // node 0..15
    const int n  = n0 + nd;
    const float nf = idn[n];

    f32x4 ar[5], dr[5];
#pragma unroll
    for (int r = 0; r < 5; ++r) {
        ar[r] = *(const f32x4*)(LB + sboff(r, nd, lg * 4)) * nf;
        dr[r] = *(const f32x4*)(LB + sboff(5 + r, nd, lg * 4)) * nf;
    }

    float pc[15], pd[15];
    {
        int k = 0;
#pragma unroll
        for (int r = 0; r < 5; ++r)
#pragma unroll
            for (int s = r; s < 5; ++s, ++k) {
                f32x4 qc = ar[r] * ar[s];
                f32x4 qd = dr[r] * dr[s];
                pc[k] = redux32((qc[0] + qc[1]) + (qc[2] + qc[3]));
                pd[k] = redux32((qd[0] + qd[1]) + (qd[2] + qd[3]));
            }
    }

    // com softmax + combine
    f32x4 zcom[5];
#pragma unroll
    for (int r = 0; r < 5; ++r) {
        float sc[5], m = -1e30f;
#pragma unroll
        for (int s = 0; s < 5; ++s) { sc[s] = pc[sidx(r, s)]; m = fmaxf(m, sc[s]); }
        float e[5], se = 0.f;
#pragma unroll
        for (int s = 0; s < 5; ++s) { e[s] = __expf(sc[s] - m); se += e[s]; }
        float inv = 1.f / se;
        f32x4 a2 = (f32x4){0.f, 0.f, 0.f, 0.f};
#pragma unroll
        for (int s = 0; s < 5; ++s) a2 += ar[s] * e[s];
        zcom[r] = a2 * inv;
    }
    // dis softmax + combine
    f32x4 zdis[5];
#pragma unroll
    for (int r = 0; r < 5; ++r) {
        float qq = pd[sidx(r, r)];
        float sd[5], md = -1e30f;
#pragma unroll
        for (int s = 0; s < 5; ++s) { sd[s] = qq - pd[sidx(r, s)]; md = fmaxf(md, sd[s]); }
        float ed[5], sed = 0.f;
#pragma unroll
        for (int s = 0; s < 5; ++s) { ed[s] = __expf(sd[s] - md); sed += ed[s]; }
        float invd = 1.f / sed;
        f32x4 d2 = (f32x4){0.f, 0.f, 0.f, 0.f};
#pragma unroll
        for (int s = 0; s < 5; ++s) d2 += dr[s] * ed[s];
        zdis[r] = dr[r] - d2 * invd;       // sum_s a*(zd_r - zd_s)
    }

    // beta = sigmoid(att_w . [z_com, z_dis] + b)
    f32x4 p4 = (f32x4){0.f, 0.f, 0.f, 0.f};
#pragma unroll
    for (int r = 0; r < 5; ++r) {
        p4 += (*(const f32x4*)&att_w[r * 128 + lg * 4]) * zcom[r];
        p4 += (*(const f32x4*)&att_w[640 + r * 128 + lg * 4]) * zdis[r];
    }
    float part = redux32((p4[0] + p4[1]) + (p4[2] + p4[3]));
    const float beta = 1.f / (1.f + __expf(-(part + att_b[0])));
    const float omb  = 1.f - beta;

#pragma unroll
    for (int r = 0; r < 5; ++r) {
        f32x4 o = zcom[r] * beta + zdis[r] * omb;
        *(f32x4*)&out[(size_t)n * 640 + r * 128 + lg * 4] = o;
    }
}

// ============================ launch ========================================
extern "C" void kernel_launch(void* const* d_in, const int* in_sizes, int n_in,
                              void* d_out, int out_size, void* d_ws, size_t ws_size,
                              hipStream_t stream)
{
    const float* x      = (const float*)d_in[0];
    const float* W_self = (const float*)d_in[1];
    const float* W_ring = (const float*)d_in[2];
    const float* WC     = (const float*)d_in[3];
    const float* WD     = (const float*)d_in[4];
    const float* att_w  = (const float*)d_in[5];
    const float* att_b  = (const float*)d_in[6];
    const float* odn    = (const float*)d_in[7];
    const float* idn    = (const float*)d_in[8];
    const int*   rows   = (const int*)d_in[9];
    const int*   cols   = (const int*)d_in[10];
    float* out = (float*)d_out;

    // ---- workspace layout (~93 MB; harness ws proven >= 118 MB in r4-r7) ----
    const size_t xs_sz  = (size_t)NN * D * 2;           // 12.8 MB (xh, xl each)
    const size_t ys_sz  = (size_t)RR * NN * D * 2;      // 25.6 MB (yh, yl each)
    const size_t pt_sz  = (size_t)10 * 128 * 128 * 2;   // 320 KB (PTh, PTl each)
    const size_t cnt_sz = (size_t)RR * NN * 4;
    const size_t rp_sz  = (size_t)RR * (NN + 1) * 4;
    const size_t cur_sz = (size_t)RR * NN * 4;
    const size_t bs_sz  = 4096;

    char* p = (char*)d_ws;
    unsigned short* xh  = (unsigned short*)p; p += xs_sz;
    unsigned short* xl  = (unsigned short*)p; p += xs_sz;
    unsigned short* yh  = (unsigned short*)p; p += ys_sz;
    unsigned short* yl  = (unsigned short*)p; p += ys_sz;
    unsigned short* PTh = (unsigned short*)p; p += pt_sz;
    unsigned short* PTl = (unsigned short*)p; p += pt_sz;
    int* cnt    = (int*)p; p += cnt_sz;
    int* rowptr = (int*)p; p += rp_sz;
    int* cursor = (int*)p; p += cur_sz;
    int* bsum   = (int*)p; p += bs_sz;
    int* perm   = (int*)p;

    // ---- input conversions (independent of CSR) ----
    convx_kernel<<<6250, 256, 0, stream>>>(x, xh, xl);
    convpt_kernel<<<640, 256, 0, stream>>>(W_self, W_ring, WC, WD, PTh, PTl);

    // ---- CSR build ----
    hipMemsetAsync(cnt, 0, cnt_sz, stream);
    hist_kernel<<<dim3(NNZ / 256, RR), 256, 0, stream>>>(rows, cnt);
    scanA_kernel<<<dim3(NCHUNK, RR), 256, 0, stream>>>(cnt, bsum);
    scanB_kernel<<<1, 256, 0, stream>>>(bsum);
    scanC_kernel<<<dim3(NCHUNK, RR), 256, 0, stream>>>(cnt, bsum, rowptr, cursor);
    fill_kernel<<<dim3(NNZ / 256, RR), 256, 0, stream>>>(rows, cols, cursor, perm);

    // ---- per-ring aggregation from x (odn folded per edge), split to bf16 ----
    gather2_kernel<<<dim3(NN / 4, RR), 256, 0, stream>>>(x, odn, rowptr, perm, yh, yl);

    // ---- fused composed-GEMM + interaction (writes d_out directly) ----
    fused2_kernel<<<NN / 16, 512, 0, stream>>>(xh, xl, yh, yl, PTh, PTl,
                                               att_w, att_b, idn, out);
}

// Round 9
// 1024.850 us; speedup vs baseline: 1.1162x; 1.1162x over previous
//
#include <hip/hip_runtime.h>
#include <hip/hip_bf16.h>

#define NN 50000
#define D 128
#define RR 4
#define NNZ 800000
#define NCHUNK 196            // ceil(NN/256)

typedef float v2f    __attribute__((ext_vector_type(2)));
typedef float f32x4  __attribute__((ext_vector_type(4)));
typedef short bf16x8 __attribute__((ext_vector_type(8)));

static __device__ __forceinline__ unsigned short f2b(float f)
{
    __hip_bfloat16 h = __float2bfloat16(f);      // RNE
    return *reinterpret_cast<unsigned short*>(&h);
}
static __device__ __forceinline__ float b2f(unsigned short u)
{
    union { unsigned u32; float f; } v; v.u32 = ((unsigned)u) << 16; return v.f;
}

// 32-lane sum reduction: 4 DPP steps (VALU pipe) + 1 ds_swizzle xor16.
static __device__ __forceinline__ float redux32(float v)
{
    int i;
    i = __builtin_amdgcn_update_dpp(0, __float_as_int(v), 0xB1, 0xF, 0xF, true);
    v += __int_as_float(i);
    i = __builtin_amdgcn_update_dpp(0, __float_as_int(v), 0x4E, 0xF, 0xF, true);
    v += __int_as_float(i);
    i = __builtin_amdgcn_update_dpp(0, __float_as_int(v), 0x141, 0xF, 0xF, true);
    v += __int_as_float(i);
    i = __builtin_amdgcn_update_dpp(0, __float_as_int(v), 0x140, 0xF, 0xF, true);
    v += __int_as_float(i);
    v += __int_as_float(__builtin_amdgcn_ds_swizzle(__float_as_int(v), 0x401F));
    return v;
}

// ============================ CSR build =====================================
__global__ __launch_bounds__(256) void hist_kernel(
    const int* __restrict__ rows, int* __restrict__ cnt)
{
    const int r = blockIdx.y;
    const int e = blockIdx.x * 256 + threadIdx.x;      // NNZ = 3125*256 exact
    atomicAdd(&cnt[r * NN + rows[(size_t)r * NNZ + e]], 1);
}

__global__ __launch_bounds__(256) void scanA_kernel(
    const int* __restrict__ cnt, int* __restrict__ bsum)
{
    const int r = blockIdx.y, bx = blockIdx.x, t = threadIdx.x;
    const int idx = bx * 256 + t;
    int v = (idx < NN) ? cnt[r * NN + idx] : 0;
#pragma unroll
    for (int off = 32; off; off >>= 1) v += __shfl_xor(v, off);
    __shared__ int ws4[4];
    if ((t & 63) == 0) ws4[t >> 6] = v;
    __syncthreads();
    if (t == 0) bsum[r * NCHUNK + bx] = ws4[0] + ws4[1] + ws4[2] + ws4[3];
}

__global__ __launch_bounds__(256) void scanB_kernel(int* __restrict__ bsum)
{
    __shared__ int s[256];
    const int t = threadIdx.x;
    for (int r = 0; r < RR; ++r) {
        int v = (t < NCHUNK) ? bsum[r * NCHUNK + t] : 0;
        s[t] = v;
        __syncthreads();
        for (int off = 1; off < 256; off <<= 1) {
            int u = (t >= off) ? s[t - off] : 0;
            __syncthreads();
            s[t] += u;
            __syncthreads();
        }
        if (t < NCHUNK) bsum[r * NCHUNK + t] = s[t] - v;   // exclusive
        __syncthreads();
    }
}

__global__ __launch_bounds__(256) void scanC_kernel(
    const int* __restrict__ cnt, const int* __restrict__ bsum,
    int* __restrict__ rowptr, int* __restrict__ cursor)
{
    const int r = blockIdx.y, bx = blockIdx.x, t = threadIdx.x;
    const int idx = bx * 256 + t;
    int v = (idx < NN) ? cnt[r * NN + idx] : 0;
    __shared__ int s[256];
    s[t] = v;
    __syncthreads();
    for (int off = 1; off < 256; off <<= 1) {
        int u = (t >= off) ? s[t - off] : 0;
        __syncthreads();
        s[t] += u;
        __syncthreads();
    }
    const int excl = bsum[r * NCHUNK + bx] + s[t] - v;
    if (idx <= NN) rowptr[r * (NN + 1) + idx] = excl;
    if (idx < NN)  cursor[r * NN + idx] = excl;
}

__global__ __launch_bounds__(256) void fill_kernel(
    const int* __restrict__ rows, const int* __restrict__ cols,
    int* __restrict__ cursor, int* __restrict__ perm)
{
    const int r = blockIdx.y;
    const int e = blockIdx.x * 256 + threadIdx.x;
    const int row = rows[(size_t)r * NNZ + e];
    const int pos = atomicAdd(&cursor[r * NN + row], 1);
    perm[(size_t)r * NNZ + pos] = cols[(size_t)r * NNZ + e];
}

// ============================ x -> bf16 hi/lo ===============================
__global__ __launch_bounds__(256) void convx_kernel(
    const float* __restrict__ x,
    unsigned short* __restrict__ xh, unsigned short* __restrict__ xl)
{
    const int i = blockIdx.x * 256 + threadIdx.x;      // over 1,600,000 float4s
    f32x4 v = ((const f32x4*)x)[i];
    ushort4 hv, lv;
#pragma unroll
    for (int j = 0; j < 4; ++j) {
        unsigned short hb = f2b(v[j]);
        ((unsigned short*)&hv)[j] = hb;
        ((unsigned short*)&lv)[j] = f2b(v[j] - b2f(hb));
    }
    ((ushort4*)xh)[i] = hv;
    ((ushort4*)xl)[i] = lv;
}

// ================== composed weights PT = (W_s^T * WX)^T ====================
// PT[m][col][k] = sum_j WX[j][col] * W_s[j][k];  m=0..4 -> WC slabs, 5..9 -> WD.
__global__ __launch_bounds__(256) void convpt_kernel(
    const float* __restrict__ Wself, const float* __restrict__ Wring,
    const float* __restrict__ WC, const float* __restrict__ WD,
    unsigned short* __restrict__ PTh, unsigned short* __restrict__ PTl)
{
    const int idx = blockIdx.x * 256 + threadIdx.x;    // 163840
    const int m   = idx >> 14;
    const int rem = idx & 16383;
    const int col = rem >> 7;
    const int kk  = rem & 127;
    const float* WX = (m < 5) ? WC : WD;
    const int s = (m < 5) ? m : m - 5;
    const float* WS = (s == 0) ? Wself : Wring + (size_t)(s - 1) * 16384;
    float acc = 0.f;
#pragma unroll 4
    for (int j = 0; j < 128; ++j)
        acc += WX[j * 128 + col] * WS[j * 128 + kk];
    unsigned short hb = f2b(acc);
    PTh[idx] = hb;
    PTl[idx] = f2b(acc - b2f(hb));
}

// ============================ CSR gather ====================================
// y[ring][row][:] = sum over edges (row,col): odn[col] * x[col][:], split bf16.
// One wave per (row, ring). 4 edges in parallel (16 lanes/edge, 2 f32x4/lane),
// 8 edges per predicated iteration -> no serial tail.
__global__ __launch_bounds__(256) void gather3_kernel(
    const float* __restrict__ x, const float* __restrict__ odn,
    const int* __restrict__ rp, const int* __restrict__ pm,
    unsigned short* __restrict__ yh, unsigned short* __restrict__ yl)
{
    const int cr = blockIdx.y;
    const int t = threadIdx.x;
    const int row = blockIdx.x * 4 + (t >> 6);      // 12500*4 = 50000 exact
    const int l  = t & 63;
    const int eg = l >> 4;                          // edge slot 0..3
    const int lg = l & 15;                          // cols lg*4 and lg*4+64
    const int* rpr = rp + (size_t)cr * (NN + 1);
    const int s = rpr[row], e = rpr[row + 1];
    const int* pmr = pm + (size_t)cr * NNZ;

    f32x4 a0 = {0.f, 0.f, 0.f, 0.f}, a1 = {0.f, 0.f, 0.f, 0.f};
    for (int i = s; i < e; i += 8) {
        const int j0 = i + eg, j1 = i + 4 + eg;
        const bool p0 = j0 < e, p1 = j1 < e;
        const int c0 = p0 ? pmr[j0] : 0;
        const int c1 = p1 ? pmr[j1] : 0;
        const float o0 = p0 ? odn[c0] : 0.f;
        const float o1 = p1 ? odn[c1] : 0.f;
        f32x4 v00 = *(const f32x4*)&x[(size_t)c0 * D + lg * 4];
        f32x4 v01 = *(const f32x4*)&x[(size_t)c0 * D + 64 + lg * 4];
        f32x4 v10 = *(const f32x4*)&x[(size_t)c1 * D + lg * 4];
        f32x4 v11 = *(const f32x4*)&x[(size_t)c1 * D + 64 + lg * 4];
        a0 += v00 * o0 + v10 * o1;
        a1 += v01 * o0 + v11 * o1;
    }
    // reduce across the 4 edge groups: xor16 then xor32
#pragma unroll
    for (int j = 0; j < 4; ++j) {
        a0[j] += __shfl_xor(a0[j], 16);
        a1[j] += __shfl_xor(a1[j], 16);
        a0[j] += __shfl_xor(a0[j], 32);
        a1[j] += __shfl_xor(a1[j], 32);
    }

    if (eg == 0) {
        ushort4 h0, l0, h1, l1;
#pragma unroll
        for (int j = 0; j < 4; ++j) {
            unsigned short b0 = f2b(a0[j]), b1 = f2b(a1[j]);
            ((unsigned short*)&h0)[j] = b0;
            ((unsigned short*)&l0)[j] = f2b(a0[j] - b2f(b0));
            ((unsigned short*)&h1)[j] = b1;
            ((unsigned short*)&l1)[j] = f2b(a1[j] - b2f(b1));
        }
        const size_t base = ((size_t)cr * NN + row) * D + lg * 4;
        *(ushort4*)&yh[base]      = h0;
        *(ushort4*)&yh[base + 64] = h1;
        *(ushort4*)&yl[base]      = l0;
        *(ushort4*)&yl[base + 64] = l1;
    }
}

// ============================ shared helpers ================================
__device__ __forceinline__ int sidx(int r, int s)
{
    if (r > s) { int t = r; r = s; s = t; }
    return r * 5 + s - (r * (r + 1)) / 2;
}

// SB[m][node][col] f32, XOR-swizzled on node.
__device__ __forceinline__ int sboff(int m, int node, int col)
{
    return (((m * 16 + node) * 128 + col) * 4) ^ ((node & 7) << 4);
}

// ======================= FUSED composed-GEMM + interaction ==================
// Block = 512 thr (8 waves) = 16 nodes. Zc/Zd[n][m] = A_s[n] @ PT_m.
// Node data (pre-split bf16 hi/lo) staged ONCE in LDS (swizzled); PT from
// global (L2-hot, 640 KB shared by all blocks). Swapped MFMA operands:
// A = PT rows (M=out-col), B = node data (N=node) -> C: node=lane&15,
// out-col = base + (lane>>4)*4+q -> b128 SB writes. Phase C: 32 lanes/node,
// f32x4 cols/lane, DPP reduce.
// LDS union (80 KB -> 2 blocks/CU): [0,40960) node hi/lo; then SB overwrites.
__global__ __launch_bounds__(512, 4) void fused3_kernel(
    const unsigned short* __restrict__ xh, const unsigned short* __restrict__ xl,
    const unsigned short* __restrict__ yh, const unsigned short* __restrict__ yl,
    const unsigned short* __restrict__ PTh, const unsigned short* __restrict__ PTl,
    const float* __restrict__ att_w, const float* __restrict__ att_b,
    const float* __restrict__ idn, float* __restrict__ out)
{
    __shared__ __align__(16) char LB[81920];

    const int t  = threadIdx.x;
    const int w  = t >> 6;
    const int l  = t & 63;
    const int lr = l & 15;
    const int lk = l >> 4;
    const int n0 = blockIdx.x * 16;

    // ---- stage node data into LDS (16B chunks, swizzled; no VALU split) ----
#pragma unroll
    for (int c = 0; c < 5; ++c) {
        const int ci  = c * 512 + t;            // [0,2560)
        const int isL = ci >= 1280;
        const int rem = ci - (isL ? 1280 : 0);
        const int s   = rem >> 8;
        const int nd  = (rem >> 4) & 15;
        const int k   = (rem & 15) * 8;
        const unsigned short* src;
        if (s == 0) src = (isL ? xl : xh) + (size_t)(n0 + nd) * D + k;
        else        src = (isL ? yl : yh) + ((size_t)(s - 1) * NN + n0 + nd) * D + k;
        f32x4 v = *(const f32x4*)src;
        const int boff = (((s * 16 + nd) * 128 + k) * 2) ^ ((nd & 7) << 4);
        *(f32x4*)(LB + (isL ? 20480 : 0) + boff) = v;
    }
    __syncthreads();

    // ---- GEMM: wave w owns out-col tile w (16 cols) of all 10 m ----
    f32x4 acc[10];
#pragma unroll
    for (int m = 0; m < 10; ++m) acc[m] = (f32x4){0.f, 0.f, 0.f, 0.f};

#pragma unroll
    for (int s = 0; s < 5; ++s) {
        const int arow = (w * 16 + lr) * 128 + lk * 8;
        const unsigned short* a0h = PTh + (size_t)s * 16384 + arow;
        const unsigned short* a0l = PTl + (size_t)s * 16384 + arow;
        const unsigned short* a1h = PTh + (size_t)(5 + s) * 16384 + arow;
        const unsigned short* a1l = PTl + (size_t)(5 + s) * 16384 + arow;
#pragma unroll
        for (int ks = 0; ks < 4; ++ks) {
            const int bbyte = (((s * 16 + lr) * 128 + ks * 32 + lk * 8) * 2)
                              ^ ((lr & 7) << 4);
            bf16x8 bh  = *(const bf16x8*)(LB + bbyte);
            bf16x8 bl  = *(const bf16x8*)(LB + 20480 + bbyte);
            bf16x8 ah0 = *(const bf16x8*)(a0h + ks * 32);
            bf16x8 al0 = *(const bf16x8*)(a0l + ks * 32);
            bf16x8 ah1 = *(const bf16x8*)(a1h + ks * 32);
            bf16x8 al1 = *(const bf16x8*)(a1l + ks * 32);
            // (Ah,Bh) + (Al,Bh) + (Ah,Bl); Al*Bl dropped (~2^-16)
            acc[s] = __builtin_amdgcn_mfma_f32_16x16x32_bf16(ah0, bh, acc[s], 0, 0, 0);
            acc[s] = __builtin_amdgcn_mfma_f32_16x16x32_bf16(al0, bh, acc[s], 0, 0, 0);
            acc[s] = __builtin_amdgcn_mfma_f32_16x16x32_bf16(ah0, bl, acc[s], 0, 0, 0);
            acc[5 + s] = __builtin_amdgcn_mfma_f32_16x16x32_bf16(ah1, bh, acc[5 + s], 0, 0, 0);
            acc[5 + s] = __builtin_amdgcn_mfma_f32_16x16x32_bf16(al1, bh, acc[5 + s], 0, 0, 0);
            acc[5 + s] = __builtin_amdgcn_mfma_f32_16x16x32_bf16(ah1, bl, acc[5 + s], 0, 0, 0);
        }
    }
    __syncthreads();   // node-LDS reads done; SB overwrites the union

    // ---- redistribute C-frags: [m][node][col], b128 writes ----
#pragma unroll
    for (int m = 0; m < 10; ++m)
        *(f32x4*)(LB + sboff(m, lr, w * 16 + lk * 4)) = acc[m];
    __syncthreads();

    // ---- phase C: 32 lanes per node ----
    const int lg = l & 31;               // cols 4lg..4lg+3
    const int nd = w * 2 + (l >> 5);     // node 0..15
    const int n  = n0 + nd;
    const float nf = idn[n];

    f32x4 ar[5], dr[5];
#pragma unroll
    for (int r = 0; r < 5; ++r) {
        ar[r] = *(const f32x4*)(LB + sboff(r, nd, lg * 4)) * nf;
        dr[r] = *(const f32x4*)(LB + sboff(5 + r, nd, lg * 4)) * nf;
    }

    float pc[15], pd[15];
    {
        int k = 0;
#pragma unroll
        for (int r = 0; r < 5; ++r)
#pragma unroll
            for (int s = r; s < 5; ++s, ++k) {
                f32x4 qc = ar[r] * ar[s];
                f32x4 qd = dr[r] * dr[s];
                pc[k] = redux32((qc[0] + qc[1]) + (qc[2] + qc[3]));
                pd[k] = redux32((qd[0] + qd[1]) + (qd[2] + qd[3]));
            }
    }

    f32x4 zcom[5];
#pragma unroll
    for (int r = 0; r < 5; ++r) {
        float sc[5], m = -1e30f;
#pragma unroll
        for (int s = 0; s < 5; ++s) { sc[s] = pc[sidx(r, s)]; m = fmaxf(m, sc[s]); }
        float e[5], se = 0.f;
#pragma unroll
        for (int s = 0; s < 5; ++s) { e[s] = __expf(sc[s] - m); se += e[s]; }
        float inv = 1.f / se;
        f32x4 a2 = (f32x4){0.f, 0.f, 0.f, 0.f};
#pragma unroll
        for (int s = 0; s < 5; ++s) a2 += ar[s] * e[s];
        zcom[r] = a2 * inv;
    }
    f32x4 zdis[5];
#pragma unroll
    for (int r = 0; r < 5; ++r) {
        float qq = pd[sidx(r, r)];
        float sd[5], md = -1e30f;
#pragma unroll
        for (int s = 0; s < 5; ++s) { sd[s] = qq - pd[sidx(r, s)]; md = fmaxf(md, sd[s]); }
        float ed[5], sed = 0.f;
#pragma unroll
        for (int s = 0; s < 5; ++s) { ed[s] = __expf(sd[s] - md); sed += ed[s]; }
        float invd = 1.f / sed;
        f32x4 d2 = (f32x4){0.f, 0.f, 0.f, 0.f};
#pragma unroll
        for (int s = 0; s < 5; ++s) d2 += dr[s] * ed[s];
        zdis[r] = dr[r] - d2 * invd;       // sum_s a*(zd_r - zd_s)
    }

    f32x4 p4 = (f32x4){0.f, 0.f, 0.f, 0.f};
#pragma unroll
    for (int r = 0; r < 5; ++r) {
        p4 += (*(const f32x4*)&att_w[r * 128 + lg * 4]) * zcom[r];
        p4 += (*(const f32x4*)&att_w[640 + r * 128 + lg * 4]) * zdis[r];
    }
    float part = redux32((p4[0] + p4[1]) + (p4[2] + p4[3]));
    const float beta = 1.f / (1.f + __expf(-(part + att_b[0])));
    const float omb  = 1.f - beta;

#pragma unroll
    for (int r = 0; r < 5; ++r) {
        f32x4 o = zcom[r] * beta + zdis[r] * omb;
        *(f32x4*)&out[(size_t)n * 640 + r * 128 + lg * 4] = o;
    }
}

// ============================ launch ========================================
extern "C" void kernel_launch(void* const* d_in, const int* in_sizes, int n_in,
                              void* d_out, int out_size, void* d_ws, size_t ws_size,
                              hipStream_t stream)
{
    const float* x      = (const float*)d_in[0];
    const float* W_self = (const float*)d_in[1];
    const float* W_ring = (const float*)d_in[2];
    const float* WC     = (const float*)d_in[3];
    const float* WD     = (const float*)d_in[4];
    const float* att_w  = (const float*)d_in[5];
    const float* att_b  = (const float*)d_in[6];
    const float* odn    = (const float*)d_in[7];
    const float* idn    = (const float*)d_in[8];
    const int*   rows   = (const int*)d_in[9];
    const int*   cols   = (const int*)d_in[10];
    float* out = (float*)d_out;

    // ---- workspace layout (~93 MB) ----
    const size_t xs_sz  = (size_t)NN * D * 2;           // xh, xl each
    const size_t ys_sz  = (size_t)RR * NN * D * 2;      // yh, yl each
    const size_t pt_sz  = (size_t)10 * 128 * 128 * 2;   // PTh, PTl each
    const size_t cnt_sz = (size_t)RR * NN * 4;
    const size_t rp_sz  = (size_t)RR * (NN + 1) * 4;
    const size_t cur_sz = (size_t)RR * NN * 4;
    const size_t bs_sz  = 4096;

    char* p = (char*)d_ws;
    unsigned short* xh  = (unsigned short*)p; p += xs_sz;
    unsigned short* xl  = (unsigned short*)p; p += xs_sz;
    unsigned short* yh  = (unsigned short*)p; p += ys_sz;
    unsigned short* yl  = (unsigned short*)p; p += ys_sz;
    unsigned short* PTh = (unsigned short*)p; p += pt_sz;
    unsigned short* PTl = (unsigned short*)p; p += pt_sz;
    int* cnt    = (int*)p; p += cnt_sz;
    int* rowptr = (int*)p; p += rp_sz;
    int* cursor = (int*)p; p += cur_sz;
    int* bsum   = (int*)p; p += bs_sz;
    int* perm   = (int*)p;

    // ---- input conversions (independent of CSR) ----
    convx_kernel<<<6250, 256, 0, stream>>>(x, xh, xl);
    convpt_kernel<<<640, 256, 0, stream>>>(W_self, W_ring, WC, WD, PTh, PTl);

    // ---- CSR build ----
    hipMemsetAsync(cnt, 0, cnt_sz, stream);
    hist_kernel<<<dim3(NNZ / 256, RR), 256, 0, stream>>>(rows, cnt);
    scanA_kernel<<<dim3(NCHUNK, RR), 256, 0, stream>>>(cnt, bsum);
    scanB_kernel<<<1, 256, 0, stream>>>(bsum);
    scanC_kernel<<<dim3(NCHUNK, RR), 256, 0, stream>>>(cnt, bsum, rowptr, cursor);
    fill_kernel<<<dim3(NNZ / 256, RR), 256, 0, stream>>>(rows, cols, cursor, perm);

    // ---- per-ring aggregation from x (odn folded per edge), split bf16 ----
    gather3_kernel<<<dim3(NN / 4, RR), 256, 0, stream>>>(x, odn, rowptr, perm, yh, yl);

    // ---- fused composed-GEMM + interaction (writes d_out directly) ----
    fused3_kernel<<<NN / 16, 512, 0, stream>>>(xh, xl, yh, yl, PTh, PTl,
                                               att_w, att_b, idn, out);
}